// Round 1
// baseline (34621.094 us; speedup 1.0000x reference)
//
#include <hip/hip_runtime.h>
#include <math.h>

#define BB 512
#define TT 256
#define DD 32
#define LL 64
#define CC 128
#define HH 512
#define HGG 512
#define HE 256
#define DIN 33
#define G3 768

#define LOG2PI_ 1.8378770664093453f

__device__ __forceinline__ float softplus_f(float x) {
  float ax = fabsf(x);
  return fmaxf(x, 0.0f) + __logf(1.0f + __expf(-ax));
}
__device__ __forceinline__ float sigmoid_f(float x) {
  return 1.0f / (1.0f + __expf(-x));
}

// ---------------- GRU scan + enc projection ----------------
// 128 blocks x 256 threads; block owns 4 batch rows; thread owns hidden unit j.
__global__ __launch_bounds__(256) void gru_kernel(
    const float* __restrict__ xs, const float* __restrict__ ts,
    const float* __restrict__ Wx, const float* __restrict__ Wh,
    const float* __restrict__ gb, const float* __restrict__ encW,
    const float* __restrict__ encb, float* __restrict__ ctx)
{
  __shared__ __align__(16) float h_s[HE][4];
  __shared__ __align__(16) float xb[DIN][4];
  const int tid = threadIdx.x;
  const int b0 = blockIdx.x * 4;
  for (int idx = tid; idx < HE*4; idx += 256) ((float*)h_s)[idx] = 0.0f;
  __syncthreads();
  const int j = tid;
  const float br = gb[j], bu = gb[HE + j], bn = gb[2*HE + j];
  for (int t = 0; t < TT; ++t) {
    // stage x_in for 4 rows
    for (int idx = tid; idx < DIN*4; idx += 256) {
      int k = idx >> 2, g = idx & 3;
      xb[k][g] = (k < DD) ? xs[((size_t)(b0+g)*TT + t)*DD + k] : ts[t];
    }
    __syncthreads();                      // (b)
    float ar[4], au[4], xn[4], hn[4];
    #pragma unroll
    for (int g = 0; g < 4; ++g) { ar[g]=br; au[g]=bu; xn[g]=bn; hn[g]=0.0f; }
    for (int k = 0; k < DIN; ++k) {
      float4 xv = *(const float4*)&xb[k][0];
      float wr = Wx[k*G3 + j];
      float wu = Wx[k*G3 + HE + j];
      float wn = Wx[k*G3 + 2*HE + j];
      ar[0] += xv.x*wr; ar[1] += xv.y*wr; ar[2] += xv.z*wr; ar[3] += xv.w*wr;
      au[0] += xv.x*wu; au[1] += xv.y*wu; au[2] += xv.z*wu; au[3] += xv.w*wu;
      xn[0] += xv.x*wn; xn[1] += xv.y*wn; xn[2] += xv.z*wn; xn[3] += xv.w*wn;
    }
    #pragma unroll 4
    for (int k = 0; k < HE; ++k) {
      float4 hv = *(const float4*)&h_s[k][0];
      float wr = Wh[k*G3 + j];
      float wu = Wh[k*G3 + HE + j];
      float wn = Wh[k*G3 + 2*HE + j];
      ar[0] += hv.x*wr; ar[1] += hv.y*wr; ar[2] += hv.z*wr; ar[3] += hv.w*wr;
      au[0] += hv.x*wu; au[1] += hv.y*wu; au[2] += hv.z*wu; au[3] += hv.w*wu;
      hn[0] += hv.x*wn; hn[1] += hv.y*wn; hn[2] += hv.z*wn; hn[3] += hv.w*wn;
    }
    float hnew[4];
    #pragma unroll
    for (int g = 0; g < 4; ++g) {
      float r = sigmoid_f(ar[g]);
      float u = sigmoid_f(au[g]);
      float n = tanhf(xn[g] + r*hn[g]);
      hnew[g] = (1.0f - u)*n + u*h_s[j][g];
    }
    __syncthreads();                      // (c) all dot reads of old h done
    #pragma unroll
    for (int g = 0; g < 4; ++g) h_s[j][g] = hnew[g];
    __syncthreads();                      // (d) new h visible
    // enc projection: ctx[t] = h_new @ encW + encb
    {
      int c = tid & 127, gp = tid >> 7;   // rows gp and gp+2
      float a0 = encb[c], a1 = encb[c];
      for (int k = 0; k < HE; ++k) {
        float w = encW[k*CC + c];
        a0 += h_s[k][gp]   * w;
        a1 += h_s[k][gp+2] * w;
      }
      ctx[((size_t)t*BB + b0 + gp)*CC + c]     = a0;
      ctx[((size_t)t*BB + b0 + gp + 2)*CC + c] = a1;
    }
  }
}

// ---------------- z0 / logqp0 / _xs[:,0,:] ----------------
__global__ __launch_bounds__(256) void z0_kernel(
  const float* __restrict__ ctx, const float* __restrict__ qzW, const float* __restrict__ qzb,
  const float* __restrict__ eps0, const float* __restrict__ pm, const float* __restrict__ pls,
  const float* __restrict__ projW, const float* __restrict__ projb,
  float* __restrict__ z, float* __restrict__ lq0, float* __restrict__ dlog,
  float* __restrict__ out)
{
  __shared__ float q_s[32][128];
  __shared__ float z0_s[32][64];
  __shared__ float c_s[32][64];
  int tid = threadIdx.x; int b0 = blockIdx.x * 32;
  for (int o = tid; o < 32*128; o += 256) {
    int r = o >> 7, n = o & 127;
    float acc = qzb[n];
    const float* crow = &ctx[(size_t)(b0 + r)*CC];
    for (int k = 0; k < CC; ++k) acc += crow[k]*qzW[k*128 + n];
    q_s[r][n] = acc;
  }
  __syncthreads();
  for (int o = tid; o < 32*64; o += 256) {
    int r = o >> 6, l = o & 63;
    float qm  = q_s[r][l];
    float qls = fminf(fmaxf(q_s[r][64+l], -20.0f), 2.0f);
    float z0v = qm + __expf(qls)*eps0[(size_t)(b0+r)*LL + l];
    z[(size_t)(b0+r)*LL + l] = z0v;
    z0_s[r][l] = z0v;
    float dp = (z0v - pm[l])*__expf(-pls[l]);
    float lpp = -0.5f*dp*dp - pls[l] - 0.5f*LOG2PI_;
    float dq = (z0v - qm)*__expf(-qls);
    float lpq = -0.5f*dq*dq - qls - 0.5f*LOG2PI_;
    c_s[r][l] = lpp - lpq;
  }
  __syncthreads();
  if (tid < 32) {
    float s = 0.0f;
    for (int l = 0; l < 64; ++l) s += c_s[tid][l];
    lq0[b0 + tid] = s;
    dlog[b0 + tid] = 0.0f;
  }
  for (int o = tid; o < 32*32; o += 256) {
    int r = o >> 5, d = o & 31;
    float acc = projb[d];
    for (int l = 0; l < LL; ++l) acc += z0_s[r][l]*projW[l*DD + d];
    out[((size_t)(b0+r)*TT + 0)*DD + d] = acc;
  }
}

// ---------------- tiled 32x64 GEMM + softplus, N=512 fixed ----------------
__device__ __forceinline__ void gemm32x64_sp(
    const float* __restrict__ A0, int ldA0, int kA,
    const float* __restrict__ A1, int ldA1,
    int K,
    const float* __restrict__ W, const float* __restrict__ bias,
    float* __restrict__ Cout,
    int r0, int n0,
    float* As, float* Ws_s)
{
  const int tid = threadIdx.x;
  const int ty = tid >> 4, tx = tid & 15;
  float acc[2][4] = {{0.f,0.f,0.f,0.f},{0.f,0.f,0.f,0.f}};
  for (int kc = 0; kc < K; kc += 32) {
    {
      int r = tid >> 3, kq = tid & 7;
      int k = kc + kq*4;
      const float* src; int ld; int kk = k;
      if (k < kA) { src = A0; ld = ldA0; }
      else        { src = A1; ld = ldA1; kk = k - kA; }
      float4 v = *(const float4*)&src[(size_t)(r0 + r)*ld + kk];
      As[(kq*4+0)*34 + r] = v.x;
      As[(kq*4+1)*34 + r] = v.y;
      As[(kq*4+2)*34 + r] = v.z;
      As[(kq*4+3)*34 + r] = v.w;
    }
    {
      int k = tid >> 4, nq = tid & 15;
      *(float4*)&Ws_s[k*64 + nq*4]      = *(const float4*)&W[(size_t)(kc+k)*512 + n0 + nq*4];
      *(float4*)&Ws_s[(k+16)*64 + nq*4] = *(const float4*)&W[(size_t)(kc+k+16)*512 + n0 + nq*4];
    }
    __syncthreads();
    #pragma unroll
    for (int k = 0; k < 32; ++k) {
      float2 a = *(const float2*)&As[k*34 + ty*2];
      float4 w = *(const float4*)&Ws_s[k*64 + tx*4];
      acc[0][0] += a.x*w.x; acc[0][1] += a.x*w.y; acc[0][2] += a.x*w.z; acc[0][3] += a.x*w.w;
      acc[1][0] += a.y*w.x; acc[1][1] += a.y*w.y; acc[1][2] += a.y*w.z; acc[1][3] += a.y*w.w;
    }
    __syncthreads();
  }
  float4 bv = *(const float4*)&bias[n0 + tx*4];
  #pragma unroll
  for (int i = 0; i < 2; ++i) {
    int row = r0 + ty*2 + i;
    float4 o;
    o.x = softplus_f(acc[i][0] + bv.x);
    o.y = softplus_f(acc[i][1] + bv.y);
    o.z = softplus_f(acc[i][2] + bv.z);
    o.w = softplus_f(acc[i][3] + bv.w);
    *(float4*)&Cout[(size_t)row*512 + n0 + tx*4] = o;
  }
}

// ---------------- SDE stage 1: layer1 f/h + diffusion g ----------------
__global__ __launch_bounds__(256) void s1_kernel(
  const float* __restrict__ z, const float* __restrict__ ctx_t,
  const float* __restrict__ fW1, const float* __restrict__ fb1,
  const float* __restrict__ hW1, const float* __restrict__ hb1,
  const float* __restrict__ gw1, const float* __restrict__ gb1,
  const float* __restrict__ gw2, const float* __restrict__ gb2,
  float* __restrict__ Af, float* __restrict__ Ah, float* __restrict__ gz)
{
  __shared__ __align__(16) float As[32*34];
  __shared__ __align__(16) float Ws_s[32*64];
  int blk = blockIdx.x;
  if (blk < 128) {
    int rt = blk >> 3, ct = blk & 7;
    gemm32x64_sp(z, LL, LL, ctx_t, CC, 192, fW1, fb1, Af, rt*32, ct*64, As, Ws_s);
  } else if (blk < 256) {
    int b2 = blk - 128; int rt = b2 >> 3, ct = b2 & 7;
    gemm32x64_sp(z, LL, LL, nullptr, 0, 64, hW1, hb1, Ah, rt*32, ct*64, As, Ws_s);
  } else {
    int b2 = blk - 256;
    int row = b2*4 + (threadIdx.x >> 6);
    int l = threadIdx.x & 63;
    float zv = z[(size_t)row*LL + l];
    float acc = 0.0f;
    const float* w1 = &gw1[l*HGG];
    const float* b1 = &gb1[l*HGG];
    const float* w2 = &gw2[l*HGG];
    for (int hh = 0; hh < HGG; hh += 4) {
      float4 a = *(const float4*)&w1[hh];
      float4 b = *(const float4*)&b1[hh];
      float4 c = *(const float4*)&w2[hh];
      acc += softplus_f(zv*a.x + b.x)*c.x;
      acc += softplus_f(zv*a.y + b.y)*c.y;
      acc += softplus_f(zv*a.z + b.z)*c.z;
      acc += softplus_f(zv*a.w + b.w)*c.w;
    }
    gz[(size_t)row*LL + l] = sigmoid_f(acc + gb2[l]);
  }
}

// ---------------- SDE stage 2: layer2 f/h ----------------
__global__ __launch_bounds__(256) void s2_kernel(
  const float* __restrict__ Af, const float* __restrict__ Ah,
  const float* __restrict__ fW2, const float* __restrict__ fb2,
  const float* __restrict__ hW2, const float* __restrict__ hb2,
  float* __restrict__ Bf, float* __restrict__ Bh)
{
  __shared__ __align__(16) float As[32*34];
  __shared__ __align__(16) float Ws_s[32*64];
  int blk = blockIdx.x;
  if (blk < 128) {
    int rt = blk >> 3, ct = blk & 7;
    gemm32x64_sp(Af, HH, HH, nullptr, 0, HH, fW2, fb2, Bf, rt*32, ct*64, As, Ws_s);
  } else {
    int b2 = blk - 128; int rt = b2 >> 3, ct = b2 & 7;
    gemm32x64_sp(Ah, HH, HH, nullptr, 0, HH, hW2, hb2, Bh, rt*32, ct*64, As, Ws_s);
  }
}

// ---------------- SDE stage 3: layer3, u, dlog, z update, proj ----------------
__global__ __launch_bounds__(256) void s3_kernel(
  const float* __restrict__ Bf, const float* __restrict__ Bh,
  const float* __restrict__ fW3T, const float* __restrict__ fb3,
  const float* __restrict__ hW3T, const float* __restrict__ hb3,
  const float* __restrict__ gz, const float* __restrict__ dW,
  const float* __restrict__ ts, const float* __restrict__ projW,
  const float* __restrict__ projb,
  float* __restrict__ z, float* __restrict__ dlog, float* __restrict__ out,
  int i)
{
  __shared__ __align__(16) float BfL[4][512];
  __shared__ __align__(16) float BhL[4][512];
  __shared__ float znL[4][64];
  int tid = threadIdx.x;
  int r0 = blockIdx.x * 4;
  for (int o = tid; o < 4*128; o += 256) {
    int g = o >> 7, q = o & 127;
    *(float4*)&BfL[g][q*4] = *(const float4*)&Bf[(size_t)(r0+g)*HH + q*4];
    *(float4*)&BhL[g][q*4] = *(const float4*)&Bh[(size_t)(r0+g)*HH + q*4];
  }
  __syncthreads();
  int w = tid >> 6, l = tid & 63;
  int row = r0 + w;
  float dt = ts[i+1] - ts[i];
  float fz = fb3[l], hz = hb3[l];
  const float* wf = &fW3T[l*HH];
  const float* wh = &hW3T[l*HH];
  for (int k = 0; k < HH; k += 4) {
    float4 bf4 = *(const float4*)&BfL[w][k];
    float4 wf4 = *(const float4*)&wf[k];
    fz += bf4.x*wf4.x + bf4.y*wf4.y + bf4.z*wf4.z + bf4.w*wf4.w;
    float4 bh4 = *(const float4*)&BhL[w][k];
    float4 wh4 = *(const float4*)&wh[k];
    hz += bh4.x*wh4.x + bh4.y*wh4.y + bh4.z*wh4.z + bh4.w*wh4.w;
  }
  float gzv = gz[(size_t)row*LL + l];
  float u = (fz - hz)/gzv;
  float sq = u*u;
  for (int off = 32; off > 0; off >>= 1) sq += __shfl_xor(sq, off);
  if (l == 0) dlog[row] += 0.5f*sq*dt;
  float dwv = dW[(size_t)row*LL + l];
  float zv  = z[(size_t)row*LL + l];
  float zn  = zv + fz*dt + gzv*sqrtf(dt)*dwv;
  z[(size_t)row*LL + l] = zn;
  znL[w][l] = zn;
  __syncthreads();
  if (tid < 128) {
    int rr = tid >> 5, d = tid & 31;
    float acc = projb[d];
    for (int ll = 0; ll < LL; ++ll) acc += znL[rr][ll]*projW[ll*DD + d];
    out[((size_t)(r0+rr)*TT + (i+1))*DD + d] = acc;
  }
}

// ---------------- W3 transpose (once per call) ----------------
__global__ void transp_kernel(const float* __restrict__ fW3, const float* __restrict__ hW3,
                              float* __restrict__ fW3T, float* __restrict__ hW3T)
{
  int idx = blockIdx.x*256 + threadIdx.x;   // 0..65535
  int a = idx >> 15;
  int r = idx & 32767;
  int l = r >> 9, k = r & 511;
  if (a == 0) fW3T[r] = fW3[k*LL + l];
  else        hW3T[r] = hW3[k*LL + l];
}

__global__ void fin_kernel(const float* __restrict__ lq0, const float* __restrict__ dlog,
                           float* __restrict__ out)
{
  int b = threadIdx.x;
  out[(size_t)BB*TT*DD + b] = lq0[b] - dlog[b];
}

extern "C" void kernel_launch(void* const* d_in, const int* in_sizes, int n_in,
                              void* d_out, int out_size, void* d_ws, size_t ws_size,
                              hipStream_t stream)
{
  const float* xs   = (const float*)d_in[0];
  const float* ts   = (const float*)d_in[1];
  const float* eps0 = (const float*)d_in[2];
  const float* dW   = (const float*)d_in[3];
  const float* gruWx= (const float*)d_in[4];
  const float* gruWh= (const float*)d_in[5];
  const float* grub = (const float*)d_in[6];
  const float* encW = (const float*)d_in[7];
  const float* encb = (const float*)d_in[8];
  const float* qzW  = (const float*)d_in[9];
  const float* qzb  = (const float*)d_in[10];
  const float* fW1  = (const float*)d_in[11];
  const float* fb1  = (const float*)d_in[12];
  const float* fW2  = (const float*)d_in[13];
  const float* fb2  = (const float*)d_in[14];
  const float* fW3  = (const float*)d_in[15];
  const float* fb3  = (const float*)d_in[16];
  const float* hW1  = (const float*)d_in[17];
  const float* hb1  = (const float*)d_in[18];
  const float* hW2  = (const float*)d_in[19];
  const float* hb2  = (const float*)d_in[20];
  const float* hW3  = (const float*)d_in[21];
  const float* hb3  = (const float*)d_in[22];
  const float* gw1  = (const float*)d_in[23];
  const float* gb1  = (const float*)d_in[24];
  const float* gw2  = (const float*)d_in[25];
  const float* gb2  = (const float*)d_in[26];
  const float* projW= (const float*)d_in[27];
  const float* projb= (const float*)d_in[28];
  const float* pm   = (const float*)d_in[29];
  const float* pls  = (const float*)d_in[30];
  float* out = (float*)d_out;
  float* ws  = (float*)d_ws;

  float* ctx  = ws;                                // T*B*C = 16,777,216
  float* z    = ctx  + (size_t)TT*BB*CC;           // B*L
  float* Af   = z    + (size_t)BB*LL;              // B*H
  float* Ah   = Af   + (size_t)BB*HH;
  float* Bf   = Ah   + (size_t)BB*HH;
  float* Bh   = Bf   + (size_t)BB*HH;
  float* gzb  = Bh   + (size_t)BB*HH;              // B*L
  float* dlog = gzb  + (size_t)BB*LL;              // B
  float* lq0  = dlog + BB;                         // B
  float* fW3T = lq0  + BB;                         // H*L
  float* hW3T = fW3T + (size_t)HH*LL;              // H*L
  // total ~17.93M floats (~71.7 MB) of ws

  hipLaunchKernelGGL(transp_kernel, dim3(256), dim3(256), 0, stream, fW3, hW3, fW3T, hW3T);
  hipLaunchKernelGGL(gru_kernel, dim3(128), dim3(256), 0, stream,
                     xs, ts, gruWx, gruWh, grub, encW, encb, ctx);
  hipLaunchKernelGGL(z0_kernel, dim3(16), dim3(256), 0, stream,
                     ctx, qzW, qzb, eps0, pm, pls, projW, projb, z, lq0, dlog, out);
  for (int i = 0; i < TT-1; ++i) {
    const float* ctx_t = ctx + (size_t)(i+1)*BB*CC;
    hipLaunchKernelGGL(s1_kernel, dim3(384), dim3(256), 0, stream,
                       z, ctx_t, fW1, fb1, hW1, hb1, gw1, gb1, gw2, gb2, Af, Ah, gzb);
    hipLaunchKernelGGL(s2_kernel, dim3(256), dim3(256), 0, stream,
                       Af, Ah, fW2, fb2, hW2, hb2, Bf, Bh);
    hipLaunchKernelGGL(s3_kernel, dim3(128), dim3(256), 0, stream,
                       Bf, Bh, fW3T, fb3, hW3T, hb3, gzb, dW + (size_t)i*BB*LL,
                       ts, projW, projb, z, dlog, out, i);
  }
  hipLaunchKernelGGL(fin_kernel, dim3(1), dim3(512), 0, stream, lq0, dlog, out);
}

// Round 2
// 32070.956 us; speedup vs baseline: 1.0795x; 1.0795x over previous
//
#include <hip/hip_runtime.h>
#include <math.h>

#define BB 512
#define TT 256
#define DD 32
#define LL 64
#define CC 128
#define HH 512
#define HGG 512
#define HE 256
#define DIN 33
#define G3 768
#define LOG2PI_ 1.8378770664093453f

__device__ __forceinline__ float softplus_f(float x) {
  float ax = fabsf(x);
  return fmaxf(x, 0.0f) + __logf(1.0f + __expf(-ax));
}
__device__ __forceinline__ float sigmoid_f(float x) {
  return 1.0f / (1.0f + __expf(-x));
}

// ---------------- prep: transpose g weights to [h][l] for coalesced loads ----
__global__ void prep_kernel(const float* __restrict__ gw1, const float* __restrict__ gb1,
                            const float* __restrict__ gw2,
                            float* __restrict__ gw1T, float* __restrict__ gb1T,
                            float* __restrict__ gw2T)
{
  int idx = blockIdx.x*256 + threadIdx.x;   // 0..32767
  int h = idx >> 6, l = idx & 63;
  gw1T[idx] = gw1[(size_t)l*HGG + h];
  gb1T[idx] = gb1[(size_t)l*HGG + h];
  gw2T[idx] = gw2[(size_t)l*HGG + h];
}

// ---------------- GRU scan + enc projection ----------------
// 128 blocks x 512 threads; block owns 4 batch rows; thread owns hidden unit
// j = tid&255 for row pair p = tid>>8 (rows 2p, 2p+1).
__global__ __launch_bounds__(512) void gru_kernel(
    const float* __restrict__ xs, const float* __restrict__ ts,
    const float* __restrict__ Wx, const float* __restrict__ Wh,
    const float* __restrict__ gb, const float* __restrict__ encW,
    const float* __restrict__ encb, float* __restrict__ ctx)
{
  __shared__ __align__(16) float h_s[HE][4];
  __shared__ __align__(16) float xb[DIN][4];
  const int tid = threadIdx.x;
  const int j = tid & 255;
  const int p = tid >> 8;
  const int b0 = blockIdx.x * 4;
  for (int idx = tid; idx < HE*4; idx += 512) ((float*)h_s)[idx] = 0.0f;
  __syncthreads();
  const float br = gb[j], bu = gb[HE + j], bn = gb[2*HE + j];
  for (int t = 0; t < TT; ++t) {
    for (int idx = tid; idx < DIN*4; idx += 512) {
      int k = idx >> 2, g = idx & 3;
      xb[k][g] = (k < DD) ? xs[((size_t)(b0+g)*TT + t)*DD + k] : ts[t];
    }
    __syncthreads();
    float ar0=br, ar1=br, au0=bu, au1=bu, xn0=bn, xn1=bn, hn0=0.f, hn1=0.f;
    for (int k = 0; k < DIN; ++k) {
      float2 xv = *(const float2*)&xb[k][2*p];
      float wr = Wx[k*G3 + j];
      float wu = Wx[k*G3 + HE + j];
      float wn = Wx[k*G3 + 2*HE + j];
      ar0 += xv.x*wr; ar1 += xv.y*wr;
      au0 += xv.x*wu; au1 += xv.y*wu;
      xn0 += xv.x*wn; xn1 += xv.y*wn;
    }
    #pragma unroll 4
    for (int k = 0; k < HE; ++k) {
      float2 hv = *(const float2*)&h_s[k][2*p];
      float wr = Wh[k*G3 + j];
      float wu = Wh[k*G3 + HE + j];
      float wn = Wh[k*G3 + 2*HE + j];
      ar0 += hv.x*wr; ar1 += hv.y*wr;
      au0 += hv.x*wu; au1 += hv.y*wu;
      hn0 += hv.x*wn; hn1 += hv.y*wn;
    }
    float h0 = h_s[j][2*p], h1 = h_s[j][2*p+1];
    float r0v = sigmoid_f(ar0), r1v = sigmoid_f(ar1);
    float u0  = sigmoid_f(au0), u1  = sigmoid_f(au1);
    float n0  = tanhf(xn0 + r0v*hn0), n1 = tanhf(xn1 + r1v*hn1);
    float hA = (1.0f - u0)*n0 + u0*h0;
    float hB = (1.0f - u1)*n1 + u1*h1;
    __syncthreads();
    h_s[j][2*p]   = hA;
    h_s[j][2*p+1] = hB;
    __syncthreads();
    {
      int c = tid & 127, r = tid >> 7;
      float a = encb[c];
      #pragma unroll 4
      for (int k = 0; k < HE; ++k) a += h_s[k][r]*encW[k*CC + c];
      ctx[((size_t)t*BB + b0 + r)*CC + c] = a;
    }
    // no end barrier needed: next-iter sync after xb staging orders everything
  }
}

// ---------------- fused SDE scan: z0 + 255 steps + outputs ----------------
// 128 blocks x 512 threads; block owns rows b0..b0+3 for the whole scan.
__global__ __launch_bounds__(512) void sde_kernel(
  const float* __restrict__ ctx, const float* __restrict__ ts,
  const float* __restrict__ eps0, const float* __restrict__ dW,
  const float* __restrict__ qzW, const float* __restrict__ qzb,
  const float* __restrict__ pm, const float* __restrict__ pls,
  const float* __restrict__ fW1, const float* __restrict__ fb1,
  const float* __restrict__ fW2, const float* __restrict__ fb2,
  const float* __restrict__ fW3, const float* __restrict__ fb3,
  const float* __restrict__ hW1, const float* __restrict__ hb1,
  const float* __restrict__ hW2, const float* __restrict__ hb2,
  const float* __restrict__ hW3, const float* __restrict__ hb3,
  const float* __restrict__ gw1T, const float* __restrict__ gb1T,
  const float* __restrict__ gw2T, const float* __restrict__ gb2,
  const float* __restrict__ projW, const float* __restrict__ projb,
  float* __restrict__ out)
{
  __shared__ __align__(16) float inT[192][4];   // z (0..63) || ctx_t (64..191), transposed
  __shared__ __align__(16) float AfT[HH][4];
  __shared__ __align__(16) float AhT[HH][4];
  __shared__ __align__(16) float BfT[HH][4];
  __shared__ __align__(16) float BhT[HH][4];
  __shared__ __align__(16) float qs[128][4];
  __shared__ float gpart[2][64][4];
  __shared__ float f3p[4][64][4];
  __shared__ float h3p[4][64][4];
  __shared__ float dlog_s[4], lq0_s[4];

  const int tid = threadIdx.x;
  const int b0 = blockIdx.x * 4;

  // ---- z0 phase ----
  { int c = tid & 127, r = tid >> 7;
    inT[64+c][r] = ctx[((size_t)(b0 + r))*CC + c]; }   // ctx[t=0]
  if (tid < 4) dlog_s[tid] = 0.0f;
  __syncthreads();
  { int n = tid & 127, r = tid >> 7;
    float acc = qzb[n];
    #pragma unroll 4
    for (int k = 0; k < CC; ++k) acc += inT[64+k][r]*qzW[k*128 + n];
    qs[n][r] = acc; }
  __syncthreads();
  if (tid < 256) {
    int r = tid >> 6, l = tid & 63;
    float qm  = qs[l][r];
    float qls = fminf(fmaxf(qs[64+l][r], -20.0f), 2.0f);
    float z0  = qm + __expf(qls)*eps0[(size_t)(b0+r)*LL + l];
    inT[l][r] = z0;
    float dp  = (z0 - pm[l])*__expf(-pls[l]);
    float lpp = -0.5f*dp*dp - pls[l] - 0.5f*LOG2PI_;
    float dq  = (z0 - qm)*__expf(-qls);
    float lpq = -0.5f*dq*dq - qls - 0.5f*LOG2PI_;
    float v = lpp - lpq;
    #pragma unroll
    for (int off = 32; off; off >>= 1) v += __shfl_xor(v, off);
    if (l == 0) lq0_s[r] = v;
  }
  __syncthreads();
  if (tid < 128) {
    int r = tid >> 5, d = tid & 31;
    float acc = projb[d];
    #pragma unroll 4
    for (int k = 0; k < LL; ++k) acc += inT[k][r]*projW[k*DD + d];
    out[((size_t)(b0+r)*TT + 0)*DD + d] = acc;
  }

  // ---- SDE scan ----
  for (int t = 0; t < TT-1; ++t) {
    // P1: stage ctx[t+1] (disjoint from z region still being read above/below)
    { int c = tid & 127, r = tid >> 7;
      inT[64+c][r] = ctx[((size_t)(t+1)*BB + b0 + r)*CC + c]; }
    __syncthreads();

    // P2: layer1 f (K=192) + h (K=64); thread = output column n
    {
      const int n = tid;
      float bf = fb1[n], bh = hb1[n];
      float af[4], ah[4];
      #pragma unroll
      for (int r = 0; r < 4; ++r) { af[r] = bf; ah[r] = bh; }
      #pragma unroll 2
      for (int k = 0; k < 192; ++k) {
        float w = fW1[k*HH + n];
        float4 a = *(const float4*)&inT[k][0];
        af[0] += a.x*w; af[1] += a.y*w; af[2] += a.z*w; af[3] += a.w*w;
      }
      #pragma unroll 2
      for (int k = 0; k < 64; ++k) {
        float w = hW1[k*HH + n];
        float4 a = *(const float4*)&inT[k][0];
        ah[0] += a.x*w; ah[1] += a.y*w; ah[2] += a.z*w; ah[3] += a.w*w;
      }
      #pragma unroll
      for (int r = 0; r < 4; ++r) {
        AfT[n][r] = softplus_f(af[r]);
        AhT[n][r] = softplus_f(ah[r]);
      }
    }
    __syncthreads();

    // P3: layer2 (path-split: waves 0-3 f, 4-7 h; 2 columns/thread) + g partials
    {
      const int pth = tid >> 8;
      const int n0  = tid & 255;
      const float* W2   = pth ? hW2 : fW2;
      const float* b2   = pth ? hb2 : fb2;
      const float* Asrc = pth ? &AhT[0][0] : &AfT[0][0];
      float*       Bdst = pth ? &BhT[0][0] : &BfT[0][0];
      float acc0[4], acc1[4];
      float bb0 = b2[n0], bb1 = b2[n0 + 256];
      #pragma unroll
      for (int r = 0; r < 4; ++r) { acc0[r] = bb0; acc1[r] = bb1; }
      #pragma unroll 2
      for (int k = 0; k < HH; ++k) {
        float4 a = *(const float4*)&Asrc[k*4];
        float w0 = W2[k*HH + n0];
        float w1 = W2[k*HH + n0 + 256];
        acc0[0] += a.x*w0; acc0[1] += a.y*w0; acc0[2] += a.z*w0; acc0[3] += a.w*w0;
        acc1[0] += a.x*w1; acc1[1] += a.y*w1; acc1[2] += a.z*w1; acc1[3] += a.w*w1;
      }
      #pragma unroll
      for (int r = 0; r < 4; ++r) {
        Bdst[n0*4 + r]        = softplus_f(acc0[r]);
        Bdst[(n0+256)*4 + r]  = softplus_f(acc1[r]);
      }
    }
    // g partials (reads only z region of inT + transposed g weights)
    {
      const int q = tid >> 8, idx = tid & 255, r = idx >> 6, l = idx & 63;
      float zv = inT[l][r];
      float acc = 0.0f;
      const int hoff = q*256;
      #pragma unroll 2
      for (int h = 0; h < 256; ++h) {
        int o = (hoff + h)*64 + l;
        acc += softplus_f(zv*gw1T[o] + gb1T[o]) * gw2T[o];
      }
      gpart[q][l][r] = acc;
    }
    __syncthreads();

    // P4: layer3, k-split 4 ways: wave w -> path w>>2, k-quarter w&3
    {
      const int pth = tid >> 8;
      const int kq  = (tid >> 6) & 3;
      const int l   = tid & 63;
      const float* Bsrc = pth ? &BhT[0][0] : &BfT[0][0];
      const float* W3   = pth ? hW3 : fW3;
      float* dst        = pth ? &h3p[0][0][0] : &f3p[0][0][0];
      float acc[4] = {0.f, 0.f, 0.f, 0.f};
      #pragma unroll 2
      for (int kk = 0; kk < 128; ++kk) {
        int k = kq*128 + kk;
        float4 b = *(const float4*)&Bsrc[k*4];
        float w = W3[k*LL + l];
        acc[0] += b.x*w; acc[1] += b.y*w; acc[2] += b.z*w; acc[3] += b.w*w;
      }
      #pragma unroll
      for (int r = 0; r < 4; ++r) dst[(kq*64 + l)*4 + r] = acc[r];
    }
    __syncthreads();

    // P5a: u, dlog, z update (wave r owns row r)
    if (tid < 256) {
      int r = tid >> 6, l = tid & 63;
      float fz = fb3[l], hz = hb3[l];
      #pragma unroll
      for (int kq = 0; kq < 4; ++kq) { fz += f3p[kq][l][r]; hz += h3p[kq][l][r]; }
      float gz = sigmoid_f(gpart[0][l][r] + gpart[1][l][r] + gb2[l]);
      float u  = (fz - hz)/gz;
      float dt = ts[t+1] - ts[t];
      float sq = u*u;
      #pragma unroll
      for (int off = 32; off; off >>= 1) sq += __shfl_xor(sq, off);
      if (l == 0) dlog_s[r] += 0.5f*sq*dt;
      float dwv = dW[((size_t)t*BB + b0 + r)*LL + l];
      float zn  = inT[l][r] + fz*dt + gz*sqrtf(dt)*dwv;
      inT[l][r] = zn;
    }
    __syncthreads();

    // P5b: projection of z_{t+1}
    if (tid < 128) {
      int r = tid >> 5, d = tid & 31;
      float acc = projb[d];
      #pragma unroll 4
      for (int k = 0; k < LL; ++k) acc += inT[k][r]*projW[k*DD + d];
      out[((size_t)(b0+r)*TT + (t+1))*DD + d] = acc;
    }
    // no end barrier: next-iter P1 writes only ctx region; first z write is
    // next P5a, which is separated by multiple barriers.
  }

  if (tid < 4) out[(size_t)BB*TT*DD + b0 + tid] = lq0_s[tid] - dlog_s[tid];
}

extern "C" void kernel_launch(void* const* d_in, const int* in_sizes, int n_in,
                              void* d_out, int out_size, void* d_ws, size_t ws_size,
                              hipStream_t stream)
{
  const float* xs   = (const float*)d_in[0];
  const float* ts   = (const float*)d_in[1];
  const float* eps0 = (const float*)d_in[2];
  const float* dW   = (const float*)d_in[3];
  const float* gruWx= (const float*)d_in[4];
  const float* gruWh= (const float*)d_in[5];
  const float* grub = (const float*)d_in[6];
  const float* encW = (const float*)d_in[7];
  const float* encb = (const float*)d_in[8];
  const float* qzW  = (const float*)d_in[9];
  const float* qzb  = (const float*)d_in[10];
  const float* fW1  = (const float*)d_in[11];
  const float* fb1  = (const float*)d_in[12];
  const float* fW2  = (const float*)d_in[13];
  const float* fb2  = (const float*)d_in[14];
  const float* fW3  = (const float*)d_in[15];
  const float* fb3  = (const float*)d_in[16];
  const float* hW1  = (const float*)d_in[17];
  const float* hb1  = (const float*)d_in[18];
  const float* hW2  = (const float*)d_in[19];
  const float* hb2  = (const float*)d_in[20];
  const float* hW3  = (const float*)d_in[21];
  const float* hb3  = (const float*)d_in[22];
  const float* gw1  = (const float*)d_in[23];
  const float* gb1  = (const float*)d_in[24];
  const float* gw2  = (const float*)d_in[25];
  const float* gb2  = (const float*)d_in[26];
  const float* projW= (const float*)d_in[27];
  const float* projb= (const float*)d_in[28];
  const float* pm   = (const float*)d_in[29];
  const float* pls  = (const float*)d_in[30];
  float* out = (float*)d_out;
  float* ws  = (float*)d_ws;

  float* ctx  = ws;                                // T*B*C = 16,777,216 floats
  float* gw1T = ctx  + (size_t)TT*BB*CC;           // 32768
  float* gb1T = gw1T + (size_t)HGG*LL;
  float* gw2T = gb1T + (size_t)HGG*LL;
  // total ~16.88M floats (~67.5 MB)

  hipLaunchKernelGGL(prep_kernel, dim3(128), dim3(256), 0, stream,
                     gw1, gb1, gw2, gw1T, gb1T, gw2T);
  hipLaunchKernelGGL(gru_kernel, dim3(128), dim3(512), 0, stream,
                     xs, ts, gruWx, gruWh, grub, encW, encb, ctx);
  hipLaunchKernelGGL(sde_kernel, dim3(128), dim3(512), 0, stream,
                     ctx, ts, eps0, dW, qzW, qzb, pm, pls,
                     fW1, fb1, fW2, fb2, fW3, fb3,
                     hW1, hb1, hW2, hb2, hW3, hb3,
                     gw1T, gb1T, gw2T, gb2, projW, projb, out);
}

// Round 3
// 24688.158 us; speedup vs baseline: 1.4023x; 1.2990x over previous
//
#include <hip/hip_runtime.h>
#include <math.h>

typedef unsigned int uint_t;
typedef unsigned short ushort_t;

#define BB 512
#define TT 256
#define DD 32
#define LL 64
#define CC 128
#define HH 512
#define HE 256
#define LOG2PI_ 1.8378770664093453f

__device__ __forceinline__ float softplus_f(float x) {
  float ax = fabsf(x);
  return fmaxf(x, 0.0f) + __logf(1.0f + __expf(-ax));
}
__device__ __forceinline__ float sigmoid_f(float x) {
  return 1.0f / (1.0f + __expf(-x));
}
__device__ __forceinline__ float bf2f(ushort_t s) {
  return __uint_as_float(((uint_t)s) << 16);
}
__device__ __forceinline__ float bflo(uint_t u) { return __uint_as_float(u << 16); }
__device__ __forceinline__ float bfhi(uint_t u) { return __uint_as_float(u & 0xffff0000u); }
__device__ __forceinline__ ushort_t f2bf(float f) {
  uint_t u = __float_as_uint(f);
  return (ushort_t)((u + 0x7fffu + ((u >> 16) & 1u)) >> 16);
}

// ---------------- prep: pack all weights to bf16 / transposed layouts -------
// seg0 W1c[256][512]  : fW1(192 rows) stacked over hW1(64 rows)
// seg1 W2c[1024][512] : fW2 stacked over hW2
// seg2 W3c[2][512][64]: fW3, hW3
// seg3 Wg[289][256][4]: (wr,wu,wn,0) per (k,j); k<33 = Wx rows, else Wh rows
// seg4 encWb[256][128]
// seg5 g12T[512][64] float2 (w1,b1) + g2T[512][64] f32 (w2)  [h][l] layout
#define S0 131072
#define S1 655360
#define S2 720896
#define S3 794880
#define S4 827648
#define S5 860416
__global__ void prep_kernel(
    const float* __restrict__ fW1, const float* __restrict__ hW1,
    const float* __restrict__ fW2, const float* __restrict__ hW2,
    const float* __restrict__ fW3, const float* __restrict__ hW3,
    const float* __restrict__ Wx,  const float* __restrict__ Wh,
    const float* __restrict__ encW,
    const float* __restrict__ gw1, const float* __restrict__ gb1,
    const float* __restrict__ gw2,
    ushort_t* __restrict__ W1c, ushort_t* __restrict__ W2c,
    ushort_t* __restrict__ W3c, ushort_t* __restrict__ Wg,
    ushort_t* __restrict__ encWb,
    float* __restrict__ g12T, float* __restrict__ g2T)
{
  int idx = blockIdx.x*256 + threadIdx.x;
  if (idx < S0) {
    int k = idx >> 9, n = idx & 511;
    float v = (k < 192) ? fW1[k*512 + n] : hW1[(k-192)*512 + n];
    W1c[idx] = f2bf(v);
  } else if (idx < S1) {
    int r = idx - S0;
    int k = r >> 9, n = r & 511;
    float v = (k < 512) ? fW2[k*512 + n] : hW2[(k-512)*512 + n];
    W2c[r] = f2bf(v);
  } else if (idx < S2) {
    int r = idx - S1;
    int p = r >> 15, k = (r >> 6) & 511, l = r & 63;
    float v = p ? hW3[k*64 + l] : fW3[k*64 + l];
    W3c[r] = f2bf(v);
  } else if (idx < S3) {
    int r = idx - S2;            // (k,j): k<289, j<256
    int k = r >> 8, j = r & 255;
    float wr, wu, wn;
    if (k < 33) { wr = Wx[k*768 + j]; wu = Wx[k*768 + 256 + j]; wn = Wx[k*768 + 512 + j]; }
    else { int kk = k - 33; wr = Wh[kk*768 + j]; wu = Wh[kk*768 + 256 + j]; wn = Wh[kk*768 + 512 + j]; }
    Wg[r*4+0] = f2bf(wr); Wg[r*4+1] = f2bf(wu); Wg[r*4+2] = f2bf(wn); Wg[r*4+3] = 0;
  } else if (idx < S4) {
    int r = idx - S3;
    encWb[r] = f2bf(encW[r]);    // [k][c] layout identical
  } else if (idx < S5) {
    int r = idx - S4;            // (h,l)
    int h = r >> 6, l = r & 63;
    g12T[r*2+0] = gw1[l*512 + h];
    g12T[r*2+1] = gb1[l*512 + h];
    g2T[r]      = gw2[l*512 + h];
  }
}

// ---------------- GRU scan + enc projection ----------------
// 256 blocks x 512 threads; block owns rows b0,b0+1. k-split-2 partials.
__global__ __launch_bounds__(512) void gru_kernel(
    const float* __restrict__ xs, const float* __restrict__ ts,
    const ushort_t* __restrict__ Wg, const float* __restrict__ gb,
    const ushort_t* __restrict__ encWb, const float* __restrict__ encb,
    float* __restrict__ ctx)
{
  __shared__ __align__(16) float hstate[HE][2];
  __shared__ __align__(16) float xv[33][2];
  __shared__ __align__(16) float par[2][HE][2][4];
  __shared__ __align__(16) float encp[2][2][CC];
  const int tid = threadIdx.x;
  const int b0 = blockIdx.x*2;
  const int j = tid & 255;
  const int kh = tid >> 8;
  for (int i = tid; i < HE*2; i += 512) ((float*)hstate)[i] = 0.f;
  __syncthreads();
  const uint2* wgu = (const uint2*)Wg;
  for (int t = 0; t < TT; ++t) {
    if (tid < 66) {
      int k = tid >> 1, r = tid & 1;
      xv[k][r] = (k < 32) ? xs[((size_t)(b0+r)*TT + t)*DD + k] : ts[t];
    }
    __syncthreads();
    {
      float pr0=0,pr1=0,pu0=0,pu1=0,px0=0,px1=0,ph0=0,ph1=0;
      if (kh == 0) {
        #pragma unroll 3
        for (int k = 0; k < 33; ++k) {
          uint2 wv = wgu[k*256 + j];
          float wr = bflo(wv.x), wu = bfhi(wv.x), wn = bflo(wv.y);
          float2 a = *(const float2*)&xv[k][0];
          pr0 += a.x*wr; pr1 += a.y*wr;
          pu0 += a.x*wu; pu1 += a.y*wu;
          px0 += a.x*wn; px1 += a.y*wn;
        }
        #pragma unroll 8
        for (int k = 33; k < 145; ++k) {
          uint2 wv = wgu[k*256 + j];
          float wr = bflo(wv.x), wu = bfhi(wv.x), wn = bflo(wv.y);
          float2 a = *(const float2*)&hstate[k-33][0];
          pr0 += a.x*wr; pr1 += a.y*wr;
          pu0 += a.x*wu; pu1 += a.y*wu;
          ph0 += a.x*wn; ph1 += a.y*wn;
        }
      } else {
        #pragma unroll 8
        for (int k = 145; k < 289; ++k) {
          uint2 wv = wgu[k*256 + j];
          float wr = bflo(wv.x), wu = bfhi(wv.x), wn = bflo(wv.y);
          float2 a = *(const float2*)&hstate[k-33][0];
          pr0 += a.x*wr; pr1 += a.y*wr;
          pu0 += a.x*wu; pu1 += a.y*wu;
          ph0 += a.x*wn; ph1 += a.y*wn;
        }
      }
      *(float4*)&par[kh][j][0][0] = make_float4(pr0,pu0,px0,ph0);
      *(float4*)&par[kh][j][1][0] = make_float4(pr1,pu1,px1,ph1);
    }
    __syncthreads();
    if (tid < 256) {
      float br = gb[j], bu = gb[256+j], bn = gb[512+j];
      #pragma unroll
      for (int r = 0; r < 2; ++r) {
        float4 p0 = *(const float4*)&par[0][j][r][0];
        float4 p1 = *(const float4*)&par[1][j][r][0];
        float rg = sigmoid_f(p0.x+p1.x+br);
        float ug = sigmoid_f(p0.y+p1.y+bu);
        float ng = tanhf(p0.z+p1.z+bn + rg*(p0.w+p1.w));
        hstate[j][r] = (1.f-ug)*ng + ug*hstate[j][r];
      }
    }
    __syncthreads();
    {
      int c = tid & 127, rr = (tid>>7)&1, k0 = (tid>>8)*128;
      float acc = 0.f;
      #pragma unroll 8
      for (int k = k0; k < k0+128; ++k)
        acc += hstate[k][rr]*bf2f(encWb[k*CC + c]);
      encp[tid>>8][rr][c] = acc;
    }
    __syncthreads();
    if (tid < 256) {
      int c = tid & 127, rr = tid>>7;
      ctx[((size_t)t*BB + b0 + rr)*CC + c] = encp[0][rr][c] + encp[1][rr][c] + encb[c];
    }
    // no trailing barrier: next-iter writers cross >=2 barriers before touching
    // anything read here.
  }
}

// ---------------- fused SDE scan ----------------
// 256 blocks x 512 threads; block owns rows b0,b0+1.
__global__ __launch_bounds__(512) void sde_kernel(
  const float* __restrict__ ctx, const float* __restrict__ ts,
  const float* __restrict__ eps0, const float* __restrict__ dW,
  const float* __restrict__ qzW, const float* __restrict__ qzb,
  const float* __restrict__ pm, const float* __restrict__ pls,
  const ushort_t* __restrict__ W1c, const float* __restrict__ fb1,
  const float* __restrict__ hb1,
  const ushort_t* __restrict__ W2c, const float* __restrict__ fb2,
  const float* __restrict__ hb2,
  const ushort_t* __restrict__ W3c, const float* __restrict__ fb3,
  const float* __restrict__ hb3,
  const float* __restrict__ g12T, const float* __restrict__ g2T,
  const float* __restrict__ gb2,
  const float* __restrict__ projW, const float* __restrict__ projb,
  float* __restrict__ out)
{
  __shared__ __align__(16) float zc[192][2];     // z rows 0-63 | ctx rows 64-191
  __shared__ __align__(16) float A2[2*512*2];    // [p][n][r]
  __shared__ __align__(16) float B2[2*512*2];
  __shared__ __align__(16) float l3p[2*4*2*64];  // [p][kq][r][l]
  __shared__ __align__(16) float gp[2*2*64];     // [q][r][l]
  __shared__ __align__(16) float dws[2][64];
  __shared__ __align__(16) float qs[128][2];
  __shared__ float dlog_s[2], lq0_s[2];

  const int tid = threadIdx.x;
  const int b0 = blockIdx.x*2;
  const uint_t* w1u = (const uint_t*)W1c;
  const uint_t* w2u = (const uint_t*)W2c;
  const uint_t* w3u = (const uint_t*)W3c;
  const float2* g12 = (const float2*)g12T;

  // ---- z0 phase ----
  if (tid < 256) { int c = tid & 127, r = tid >> 7;
    zc[64+c][r] = ctx[((size_t)(b0+r))*CC + c]; }
  if (tid < 2) dlog_s[tid] = 0.f;
  __syncthreads();
  if (tid < 256) {
    int n = tid & 127, r = tid >> 7;
    float acc = qzb[n];
    #pragma unroll 4
    for (int k = 0; k < CC; ++k) acc += zc[64+k][r]*qzW[k*128 + n];
    qs[n][r] = acc;
  }
  __syncthreads();
  if (tid < 128) {
    int r = tid >> 6, l = tid & 63;
    float qm  = qs[l][r];
    float qls = fminf(fmaxf(qs[64+l][r], -20.0f), 2.0f);
    float z0  = qm + __expf(qls)*eps0[(size_t)(b0+r)*LL + l];
    zc[l][r] = z0;
    float dp  = (z0 - pm[l])*__expf(-pls[l]);
    float lpp = -0.5f*dp*dp - pls[l] - 0.5f*LOG2PI_;
    float dq  = (z0 - qm)*__expf(-qls);
    float lpq = -0.5f*dq*dq - qls - 0.5f*LOG2PI_;
    float v = lpp - lpq;
    #pragma unroll
    for (int off = 32; off; off >>= 1) v += __shfl_xor(v, off);
    if (l == 0) lq0_s[r] = v;
  }
  __syncthreads();
  if (tid < 64) {
    int r = tid >> 5, d = tid & 31;
    float acc = projb[d];
    #pragma unroll 4
    for (int k = 0; k < LL; ++k) acc += zc[k][r]*projW[k*DD + d];
    out[((size_t)(b0+r)*TT + 0)*DD + d] = acc;
  }

  // ---- SDE scan ----
  for (int t = 0; t < TT-1; ++t) {
    // P1: stage ctx[t+1] + dW[t]
    if (tid < 256) { int c = tid & 127, r = tid >> 7;
      zc[64+c][r] = ctx[((size_t)(t+1)*BB + b0 + r)*CC + c]; }
    else if (tid < 384) { int ix = tid - 256; int r = ix >> 6, l = ix & 63;
      dws[r][l] = dW[((size_t)t*BB + b0 + r)*LL + l]; }
    __syncthreads();

    float gacc = 0.f;
    const int gl = tid & 63, gr = (tid >> 6) & 1, gq = (tid >> 7) & 1; // tid>=256 roles

    // P2: layer1. f: threads 0-255 (K=192). h: threads 256-511 (K=64) + g chunk A.
    if (tid < 256) {
      const int ncol = tid, n2 = ncol*2;
      float b0v = fb1[n2], b1v = fb1[n2+1];
      float a00=0,a01=0,a10=0,a11=0;
      #pragma unroll 8
      for (int k = 0; k < 192; ++k) {
        uint_t u = w1u[k*256 + ncol];
        float w0 = bflo(u), w1 = bfhi(u);
        float2 a = *(const float2*)&zc[k][0];
        a00 += a.x*w0; a01 += a.x*w1; a10 += a.y*w0; a11 += a.y*w1;
      }
      *(float4*)&A2[(0*512 + n2)*2] =
        make_float4(softplus_f(a00+b0v), softplus_f(a10+b0v),
                    softplus_f(a01+b1v), softplus_f(a11+b1v));
    } else {
      const int ncol = tid & 255, n2 = ncol*2;
      float b0v = hb1[n2], b1v = hb1[n2+1];
      float a00=0,a01=0,a10=0,a11=0;
      #pragma unroll 8
      for (int k = 0; k < 64; ++k) {
        uint_t u = w1u[(192+k)*256 + ncol];
        float w0 = bflo(u), w1 = bfhi(u);
        float2 a = *(const float2*)&zc[k][0];
        a00 += a.x*w0; a01 += a.x*w1; a10 += a.y*w0; a11 += a.y*w1;
      }
      *(float4*)&A2[(1*512 + n2)*2] =
        make_float4(softplus_f(a00+b0v), softplus_f(a10+b0v),
                    softplus_f(a01+b1v), softplus_f(a11+b1v));
      // g chunk A: h in [gq*85, gq*85+85)
      float zv = zc[gl][gr];
      int h0 = gq*85, h1 = h0 + 85;
      #pragma unroll 4
      for (int h = h0; h < h1; ++h) {
        float2 wb = g12[h*64 + gl];
        gacc += softplus_f(zv*wb.x + wb.y) * g2T[h*64 + gl];
      }
    }
    __syncthreads();

    // P3: layer2, all 512 threads. p = tid>>8.
    {
      const int p = tid >> 8, ncol = tid & 255, n2 = ncol*2;
      const float* bb = p ? hb2 : fb2;
      float b0v = bb[n2], b1v = bb[n2+1];
      float a00=0,a01=0,a10=0,a11=0;
      #pragma unroll 8
      for (int k = 0; k < HH; ++k) {
        uint_t u = w2u[(p*512 + k)*256 + ncol];
        float w0 = bflo(u), w1 = bfhi(u);
        float2 a = *(const float2*)&A2[(p*512 + k)*2];
        a00 += a.x*w0; a01 += a.x*w1; a10 += a.y*w0; a11 += a.y*w1;
      }
      *(float4*)&B2[(p*512 + n2)*2] =
        make_float4(softplus_f(a00+b0v), softplus_f(a10+b0v),
                    softplus_f(a01+b1v), softplus_f(a11+b1v));
    }
    __syncthreads();

    // P4: layer3 partials (threads 0-255) ; g chunk B (threads 256-511)
    if (tid < 256) {
      const int p = tid >> 7, kq = (tid >> 5) & 3, ng = tid & 31, c2 = ng*2;
      float a00=0,a01=0,a10=0,a11=0;
      #pragma unroll 8
      for (int i = 0; i < 128; ++i) {
        int k = kq*128 + i;
        uint_t u = w3u[(p*512 + k)*32 + ng];
        float w0 = bflo(u), w1 = bfhi(u);
        float2 bv = *(const float2*)&B2[(p*512 + k)*2];
        a00 += bv.x*w0; a01 += bv.x*w1; a10 += bv.y*w0; a11 += bv.y*w1;
      }
      *(float2*)&l3p[((p*4+kq)*2 + 0)*64 + c2] = make_float2(a00, a01);
      *(float2*)&l3p[((p*4+kq)*2 + 1)*64 + c2] = make_float2(a10, a11);
    } else {
      float zv = zc[gl][gr];
      int h0 = 170 + gq*171, h1 = h0 + 171;
      #pragma unroll 4
      for (int h = h0; h < h1; ++h) {
        float2 wb = g12[h*64 + gl];
        gacc += softplus_f(zv*wb.x + wb.y) * g2T[h*64 + gl];
      }
      gp[(gq*2 + gr)*64 + gl] = gacc;
    }
    __syncthreads();

    // P5: epilogue: u, dlog, z update
    if (tid < 128) {
      int r = tid >> 6, l = tid & 63;
      float fz = fb3[l], hz = hb3[l];
      #pragma unroll
      for (int kq = 0; kq < 4; ++kq) {
        fz += l3p[((0*4+kq)*2 + r)*64 + l];
        hz += l3p[((1*4+kq)*2 + r)*64 + l];
      }
      float gzv = sigmoid_f(gp[(0*2+r)*64 + l] + gp[(1*2+r)*64 + l] + gb2[l]);
      float dt = ts[t+1] - ts[t];
      float u = (fz - hz)/gzv;
      float sq = u*u;
      #pragma unroll
      for (int off = 32; off; off >>= 1) sq += __shfl_xor(sq, off);
      if (l == 0) dlog_s[r] += 0.5f*sq*dt;
      float zn = zc[l][r] + fz*dt + gzv*sqrtf(dt)*dws[r][l];
      zc[l][r] = zn;
    }
    __syncthreads();

    // P6: projection of z_{t+1}
    if (tid < 64) {
      int r = tid >> 5, d = tid & 31;
      float acc = projb[d];
      #pragma unroll 4
      for (int k = 0; k < LL; ++k) acc += zc[k][r]*projW[k*DD + d];
      out[((size_t)(b0+r)*TT + (t+1))*DD + d] = acc;
    }
    // no trailing barrier: next P1 writes only ctx region / dws, both
    // protected by the P5-end barrier relative to their readers.
  }

  if (tid < 2) out[(size_t)BB*TT*DD + b0 + tid] = lq0_s[tid] - dlog_s[tid];
}

extern "C" void kernel_launch(void* const* d_in, const int* in_sizes, int n_in,
                              void* d_out, int out_size, void* d_ws, size_t ws_size,
                              hipStream_t stream)
{
  const float* xs   = (const float*)d_in[0];
  const float* ts   = (const float*)d_in[1];
  const float* eps0 = (const float*)d_in[2];
  const float* dW   = (const float*)d_in[3];
  const float* gruWx= (const float*)d_in[4];
  const float* gruWh= (const float*)d_in[5];
  const float* grub = (const float*)d_in[6];
  const float* encW = (const float*)d_in[7];
  const float* encb = (const float*)d_in[8];
  const float* qzW  = (const float*)d_in[9];
  const float* qzb  = (const float*)d_in[10];
  const float* fW1  = (const float*)d_in[11];
  const float* fb1  = (const float*)d_in[12];
  const float* fW2  = (const float*)d_in[13];
  const float* fb2  = (const float*)d_in[14];
  const float* fW3  = (const float*)d_in[15];
  const float* fb3  = (const float*)d_in[16];
  const float* hW1  = (const float*)d_in[17];
  const float* hb1  = (const float*)d_in[18];
  const float* hW2  = (const float*)d_in[19];
  const float* hb2  = (const float*)d_in[20];
  const float* hW3  = (const float*)d_in[21];
  const float* hb3  = (const float*)d_in[22];
  const float* gw1  = (const float*)d_in[23];
  const float* gb1  = (const float*)d_in[24];
  const float* gw2  = (const float*)d_in[25];
  const float* gb2  = (const float*)d_in[26];
  const float* projW= (const float*)d_in[27];
  const float* projb= (const float*)d_in[28];
  const float* pm   = (const float*)d_in[29];
  const float* pls  = (const float*)d_in[30];
  float* out = (float*)d_out;
  float* ws  = (float*)d_ws;

  float* ctx  = ws;                          // 16,777,216 floats
  float* g12T = ctx  + (size_t)16777216;     // 65,536 floats (float2[512*64])
  float* g2T  = g12T + 65536;                // 32,768 floats
  ushort_t* W1c   = (ushort_t*)(g2T + 32768);// 131,072 ushorts
  ushort_t* W2c   = W1c + 131072;            // 524,288
  ushort_t* W3c   = W2c + 524288;            // 65,536
  ushort_t* Wg    = W3c + 65536;             // 295,936
  ushort_t* encWb = Wg  + 295936;            // 32,768

  hipLaunchKernelGGL(prep_kernel, dim3(3361), dim3(256), 0, stream,
                     fW1, hW1, fW2, hW2, fW3, hW3, gruWx, gruWh, encW,
                     gw1, gb1, gw2, W1c, W2c, W3c, Wg, encWb, g12T, g2T);
  hipLaunchKernelGGL(gru_kernel, dim3(256), dim3(512), 0, stream,
                     xs, ts, Wg, grub, encWb, encb, ctx);
  hipLaunchKernelGGL(sde_kernel, dim3(256), dim3(512), 0, stream,
                     ctx, ts, eps0, dW, qzW, qzb, pm, pls,
                     W1c, fb1, hb1, W2c, fb2, hb2, W3c, fb3, hb3,
                     g12T, g2T, gb2, projW, projb, out);
}

// Round 4
// 9733.576 us; speedup vs baseline: 3.5569x; 2.5364x over previous
//
#include <hip/hip_runtime.h>
#include <math.h>

typedef unsigned int uint_t;
typedef unsigned short ushort_t;
typedef __bf16 bf16x8 __attribute__((ext_vector_type(8)));
typedef float f32x4 __attribute__((ext_vector_type(4)));

#define BB 512
#define TT 256
#define DD 32
#define LL 64
#define CC 128
#define HH 512
#define HE 256
#define LOG2PI_ 1.8378770664093453f
#define GK 4097
#define GSCALE 32.0f
#define GZMIN (-64.0f)

__device__ __forceinline__ float softplus_f(float x) {
  float ax = fabsf(x);
  return fmaxf(x, 0.0f) + __logf(1.0f + __expf(-ax));
}
__device__ __forceinline__ float sigmoid_f(float x) {
  return 1.0f / (1.0f + __expf(-x));
}
__device__ __forceinline__ float bf2f(ushort_t s) {
  return __uint_as_float(((uint_t)s) << 16);
}
__device__ __forceinline__ float bflo(uint_t u) { return __uint_as_float(u << 16); }
__device__ __forceinline__ float bfhi(uint_t u) { return __uint_as_float(u & 0xffff0000u); }
__device__ __forceinline__ ushort_t f2bf(float f) {
  uint_t u = __float_as_uint(f);
  return (ushort_t)((u + 0x7fffu + ((u >> 16) & 1u)) >> 16);
}

#define MFMA_B16(a,b,c) __builtin_amdgcn_mfma_f32_16x16x32_bf16(a,b,c,0,0,0)

// ---------------- prep: pack weights into MFMA fragment order -------------
// Fragment (16x16x32, bf16): A/B lane l, reg j:  k = (l>>4)*8 + j, col/row = l&15.
// B-frag for (ks, nt): element = W[k = ks*32 + (l>>4)*8 + j][n = nt*16 + (l&15)]
// stored at frag*512 + l*8 + j  -> one wave reads a frag with one dwordx4/lane.
__global__ void prep_kernel(
    const float* __restrict__ fW1, const float* __restrict__ hW1,
    const float* __restrict__ fW2, const float* __restrict__ hW2,
    const float* __restrict__ fW3, const float* __restrict__ hW3,
    const float* __restrict__ Wx,  const float* __restrict__ Wh,
    const float* __restrict__ encW,
    ushort_t* __restrict__ W1fp, ushort_t* __restrict__ W1hp,
    ushort_t* __restrict__ W2fp, ushort_t* __restrict__ W2hp,
    ushort_t* __restrict__ W3fp, ushort_t* __restrict__ W3hp,
    ushort_t* __restrict__ Wg, ushort_t* __restrict__ encWb)
{
  int idx = blockIdx.x*256 + threadIdx.x;
  if (idx < 98304) {                       // W1fp: 6 ks x 32 nt
    int f = idx >> 9, e = idx & 511;
    int ks = f >> 5, nt = f & 31, l = e >> 3, j = e & 7;
    int k = ks*32 + ((l>>4)<<3) + j, n = nt*16 + (l & 15);
    W1fp[idx] = f2bf(fW1[k*512 + n]);
  } else if (idx < 131072) {               // W1hp: 2 ks x 32 nt
    int r = idx - 98304;
    int f = r >> 9, e = r & 511;
    int ks = f >> 5, nt = f & 31, l = e >> 3, j = e & 7;
    int k = ks*32 + ((l>>4)<<3) + j, n = nt*16 + (l & 15);
    W1hp[r] = f2bf(hW1[k*512 + n]);
  } else if (idx < 393216) {               // W2fp: 16 ks x 32 nt
    int r = idx - 131072;
    int f = r >> 9, e = r & 511;
    int ks = f >> 5, nt = f & 31, l = e >> 3, j = e & 7;
    int k = ks*32 + ((l>>4)<<3) + j, n = nt*16 + (l & 15);
    W2fp[r] = f2bf(fW2[k*512 + n]);
  } else if (idx < 655360) {               // W2hp
    int r = idx - 393216;
    int f = r >> 9, e = r & 511;
    int ks = f >> 5, nt = f & 31, l = e >> 3, j = e & 7;
    int k = ks*32 + ((l>>4)<<3) + j, n = nt*16 + (l & 15);
    W2hp[r] = f2bf(hW2[k*512 + n]);
  } else if (idx < 688128) {               // W3fp: 16 ks x 4 nt
    int r = idx - 655360;
    int f = r >> 9, e = r & 511;
    int ks = f >> 2, nt = f & 3, l = e >> 3, j = e & 7;
    int k = ks*32 + ((l>>4)<<3) + j, n = nt*16 + (l & 15);
    W3fp[r] = f2bf(fW3[k*64 + n]);
  } else if (idx < 720896) {               // W3hp
    int r = idx - 688128;
    int f = r >> 9, e = r & 511;
    int ks = f >> 2, nt = f & 3, l = e >> 3, j = e & 7;
    int k = ks*32 + ((l>>4)<<3) + j, n = nt*16 + (l & 15);
    W3hp[r] = f2bf(hW3[k*64 + n]);
  } else if (idx < 794880) {               // Wg (GRU): (k<289, j<256) x4
    int r = idx - 720896;
    int k = r >> 8, j = r & 255;
    float wr, wu, wn;
    if (k < 33) { wr = Wx[k*768 + j]; wu = Wx[k*768 + 256 + j]; wn = Wx[k*768 + 512 + j]; }
    else { int kk = k - 33; wr = Wh[kk*768 + j]; wu = Wh[kk*768 + 256 + j]; wn = Wh[kk*768 + 512 + j]; }
    Wg[r*4+0] = f2bf(wr); Wg[r*4+1] = f2bf(wu); Wg[r*4+2] = f2bf(wn); Wg[r*4+3] = 0;
  } else if (idx < 827648) {               // encWb
    int r = idx - 794880;
    encWb[r] = f2bf(encW[r]);
  }
}

// ---------------- g-function lookup table -----------------------------------
// gtab[l][i] = sigmoid( sum_h softplus(z_i*gw1[l,h]+gb1[l,h])*gw2[l,h] + gb2[l] )
__global__ void lut_kernel(const float* __restrict__ gw1, const float* __restrict__ gb1,
                           const float* __restrict__ gw2, const float* __restrict__ gb2,
                           float* __restrict__ gtab)
{
  int idx = blockIdx.x*256 + threadIdx.x;
  if (idx >= 64*GK) return;
  int l = idx / GK, i = idx - l*GK;
  float z = GZMIN + (float)i*(1.0f/GSCALE);
  float s = 0.f;
  for (int h = 0; h < 512; ++h)
    s += softplus_f(z*gw1[l*512+h] + gb1[l*512+h]) * gw2[l*512+h];
  gtab[idx] = sigmoid_f(s + gb2[l]);
}

// ---------------- GRU scan + enc projection (unchanged, passing) ------------
__global__ __launch_bounds__(512) void gru_kernel(
    const float* __restrict__ xs, const float* __restrict__ ts,
    const ushort_t* __restrict__ Wg, const float* __restrict__ gb,
    const ushort_t* __restrict__ encWb, const float* __restrict__ encb,
    float* __restrict__ ctx)
{
  __shared__ __align__(16) float hstate[HE][2];
  __shared__ __align__(16) float xv[33][2];
  __shared__ __align__(16) float par[2][HE][2][4];
  __shared__ __align__(16) float encp[2][2][CC];
  const int tid = threadIdx.x;
  const int b0 = blockIdx.x*2;
  const int j = tid & 255;
  const int kh = tid >> 8;
  for (int i = tid; i < HE*2; i += 512) ((float*)hstate)[i] = 0.f;
  __syncthreads();
  const uint2* wgu = (const uint2*)Wg;
  for (int t = 0; t < TT; ++t) {
    if (tid < 66) {
      int k = tid >> 1, r = tid & 1;
      xv[k][r] = (k < 32) ? xs[((size_t)(b0+r)*TT + t)*DD + k] : ts[t];
    }
    __syncthreads();
    {
      float pr0=0,pr1=0,pu0=0,pu1=0,px0=0,px1=0,ph0=0,ph1=0;
      if (kh == 0) {
        #pragma unroll 3
        for (int k = 0; k < 33; ++k) {
          uint2 wv = wgu[k*256 + j];
          float wr = bflo(wv.x), wu = bfhi(wv.x), wn = bflo(wv.y);
          float2 a = *(const float2*)&xv[k][0];
          pr0 += a.x*wr; pr1 += a.y*wr;
          pu0 += a.x*wu; pu1 += a.y*wu;
          px0 += a.x*wn; px1 += a.y*wn;
        }
        #pragma unroll 8
        for (int k = 33; k < 145; ++k) {
          uint2 wv = wgu[k*256 + j];
          float wr = bflo(wv.x), wu = bfhi(wv.x), wn = bflo(wv.y);
          float2 a = *(const float2*)&hstate[k-33][0];
          pr0 += a.x*wr; pr1 += a.y*wr;
          pu0 += a.x*wu; pu1 += a.y*wu;
          ph0 += a.x*wn; ph1 += a.y*wn;
        }
      } else {
        #pragma unroll 8
        for (int k = 145; k < 289; ++k) {
          uint2 wv = wgu[k*256 + j];
          float wr = bflo(wv.x), wu = bfhi(wv.x), wn = bflo(wv.y);
          float2 a = *(const float2*)&hstate[k-33][0];
          pr0 += a.x*wr; pr1 += a.y*wr;
          pu0 += a.x*wu; pu1 += a.y*wu;
          ph0 += a.x*wn; ph1 += a.y*wn;
        }
      }
      *(float4*)&par[kh][j][0][0] = make_float4(pr0,pu0,px0,ph0);
      *(float4*)&par[kh][j][1][0] = make_float4(pr1,pu1,px1,ph1);
    }
    __syncthreads();
    if (tid < 256) {
      float br = gb[j], bu = gb[256+j], bn = gb[512+j];
      #pragma unroll
      for (int r = 0; r < 2; ++r) {
        float4 p0 = *(const float4*)&par[0][j][r][0];
        float4 p1 = *(const float4*)&par[1][j][r][0];
        float rg = sigmoid_f(p0.x+p1.x+br);
        float ug = sigmoid_f(p0.y+p1.y+bu);
        float ng = tanhf(p0.z+p1.z+bn + rg*(p0.w+p1.w));
        hstate[j][r] = (1.f-ug)*ng + ug*hstate[j][r];
      }
    }
    __syncthreads();
    {
      int c = tid & 127, rr = (tid>>7)&1, k0 = (tid>>8)*128;
      float acc = 0.f;
      #pragma unroll 8
      for (int k = k0; k < k0+128; ++k)
        acc += hstate[k][rr]*bf2f(encWb[k*CC + c]);
      encp[tid>>8][rr][c] = acc;
    }
    __syncthreads();
    if (tid < 256) {
      int c = tid & 127, rr = tid>>7;
      ctx[((size_t)t*BB + b0 + rr)*CC + c] = encp[0][rr][c] + encp[1][rr][c] + encb[c];
    }
  }
}

// ---------------- fused SDE scan: MFMA, 32 blocks x 16 rows ------------------
// A-frag scatter address for element (row,k): (k>>5)*512 + (row + ((k>>3)&3)*16)*8 + (k&7)
#define AP_SCAT(row,k) (((k)>>5)*512 + ((row) + (((k)>>3)&3)*16)*8 + ((k)&7))

#define P1E(av, ahv, NT4) { \
  int c = w*64 + (NT4)*16 + (lane & 15); \
  float bfv = fb1[c], bhv = hb1[c]; \
  _Pragma("unroll") \
  for (int j = 0; j < 4; ++j) { \
    int r = (lane>>4)*4 + j; \
    int si = AP_SCAT(r, c); \
    AfP[si] = (__bf16)softplus_f((av)[j] + bfv); \
    AhP[si] = (__bf16)softplus_f((ahv)[j] + bhv); \
  } }

#define P2E(av, NT4, biasp) { \
  int c = w*64 + (NT4)*16 + (lane & 15); \
  float bv = (biasp)[c]; \
  _Pragma("unroll") \
  for (int j = 0; j < 4; ++j) { \
    int r = (lane>>4)*4 + j; \
    Bsh[AP_SCAT(r, c)] = (__bf16)softplus_f((av)[j] + bv); \
  } }

__global__ __launch_bounds__(512) void sde_kernel(
  const float* __restrict__ ctx, const float* __restrict__ ts,
  const float* __restrict__ eps0, const float* __restrict__ dW,
  const float* __restrict__ qzW, const float* __restrict__ qzb,
  const float* __restrict__ pm, const float* __restrict__ pls,
  const ushort_t* __restrict__ W1fp, const ushort_t* __restrict__ W1hp,
  const ushort_t* __restrict__ W2fp, const ushort_t* __restrict__ W2hp,
  const ushort_t* __restrict__ W3fp, const ushort_t* __restrict__ W3hp,
  const float* __restrict__ fb1, const float* __restrict__ hb1,
  const float* __restrict__ fb2, const float* __restrict__ hb2,
  const float* __restrict__ fb3, const float* __restrict__ hb3,
  const float* __restrict__ gtab,
  const float* __restrict__ gw1, const float* __restrict__ gb1,
  const float* __restrict__ gw2, const float* __restrict__ gb2,
  const float* __restrict__ projW, const float* __restrict__ projb,
  float* __restrict__ out)
{
  __shared__ __align__(16) unsigned char smem[61568];
  __bf16* AfP = (__bf16*)smem;                 // 8192 bf16; head 3072 doubles as Apack
  __bf16* AhP = (__bf16*)(smem + 16384);       // 8192 bf16
  __bf16* Bsh = (__bf16*)(smem + 32768);       // 8192 bf16 (shared f/h B-buffer)
  float*  z_s = (float*)(smem + 49152);        // 16x64
  float*  fzL = (float*)(smem + 53248);        // 16x64
  float*  hzL = (float*)(smem + 57344);        // 16x64
  float*  dlog_s = (float*)(smem + 61440);     // 16
  float*  lq0_s  = (float*)(smem + 61504);     // 16
  __bf16* Apack = AfP;

  const int tid = threadIdx.x;
  const int b0 = blockIdx.x * 16;
  const int w = tid >> 6, lane = tid & 63;
  const int erow = tid >> 5, el0 = (tid & 31) * 2;

  // ---- z0 phase ----
  {
    float* ctx0f = (float*)AhP;   // 2048 f32 scratch
    float* qf    = (float*)Bsh;   // 2048 f32 scratch
    for (int o = tid; o < 2048; o += 512) {
      int r = o >> 7, c = o & 127;
      ctx0f[o] = ctx[(size_t)(b0 + r)*CC + c];
    }
    if (tid < 16) dlog_s[tid] = 0.f;
    __syncthreads();
    for (int o = tid; o < 2048; o += 512) {
      int r = o >> 7, n = o & 127;
      float acc = qzb[n];
      #pragma unroll 4
      for (int k = 0; k < CC; ++k) acc += ctx0f[r*128 + k]*qzW[k*128 + n];
      qf[o] = acc;
    }
    __syncthreads();
    {
      float v = 0.f;
      #pragma unroll
      for (int e = 0; e < 2; ++e) {
        int l = el0 + e;
        float qm  = qf[erow*128 + l];
        float qls = fminf(fmaxf(qf[erow*128 + 64 + l], -20.f), 2.f);
        float z0  = qm + __expf(qls)*eps0[(size_t)(b0+erow)*LL + l];
        z_s[erow*64 + l] = z0;
        Apack[AP_SCAT(erow, l)] = (__bf16)z0;
        float dp = (z0 - pm[l])*__expf(-pls[l]);
        float dq = (z0 - qm)*__expf(-qls);
        v += (-0.5f*dp*dp - pls[l]) - (-0.5f*dq*dq - qls);
      }
      #pragma unroll
      for (int off = 16; off; off >>= 1) v += __shfl_xor(v, off);
      if ((tid & 31) == 0) lq0_s[erow] = v;
    }
    __syncthreads();
    {
      int row = tid >> 5, d0 = tid & 31;
      float acc = projb[d0];
      #pragma unroll 8
      for (int l = 0; l < 64; ++l) acc += z_s[row*64 + l]*projW[l*DD + d0];
      out[((size_t)(b0+row)*TT + 0)*DD + d0] = acc;
    }
  }

  // ---- SDE scan ----
  for (int t = 0; t < TT-1; ++t) {
    // P0: stage ctx[t+1] into Apack ctx region (k = 64..191)
    for (int o = tid; o < 2048; o += 512) {
      int r = o >> 7, c = o & 127;
      float v = ctx[((size_t)(t+1)*BB + b0 + r)*CC + c];
      int k = 64 + c;
      Apack[AP_SCAT(r, k)] = (__bf16)v;
    }
    __syncthreads();                                   // bar1

    // P1: layer1 MFMA (f: K=192, h: K=64), wave w owns cols w*64..w*64+63
    f32x4 af0={0,0,0,0}, af1={0,0,0,0}, af2={0,0,0,0}, af3={0,0,0,0};
    f32x4 ah0={0,0,0,0}, ah1={0,0,0,0}, ah2={0,0,0,0}, ah3={0,0,0,0};
    #pragma unroll
    for (int ks = 0; ks < 6; ++ks) {
      bf16x8 a = *(const bf16x8*)&Apack[ks*512 + lane*8];
      const ushort_t* wb = W1fp + (size_t)(ks*32 + w*4)*512 + lane*8;
      af0 = MFMA_B16(a, *(const bf16x8*)(wb       ), af0);
      af1 = MFMA_B16(a, *(const bf16x8*)(wb +  512), af1);
      af2 = MFMA_B16(a, *(const bf16x8*)(wb + 1024), af2);
      af3 = MFMA_B16(a, *(const bf16x8*)(wb + 1536), af3);
      if (ks < 2) {
        const ushort_t* hb = W1hp + (size_t)(ks*32 + w*4)*512 + lane*8;
        ah0 = MFMA_B16(a, *(const bf16x8*)(hb       ), ah0);
        ah1 = MFMA_B16(a, *(const bf16x8*)(hb +  512), ah1);
        ah2 = MFMA_B16(a, *(const bf16x8*)(hb + 1024), ah2);
        ah3 = MFMA_B16(a, *(const bf16x8*)(hb + 1536), ah3);
      }
    }
    __syncthreads();                                   // bar2 (Apack reads done)
    P1E(af0, ah0, 0) P1E(af1, ah1, 1) P1E(af2, ah2, 2) P1E(af3, ah3, 3)
    __syncthreads();                                   // bar3

    // P2f: layer2 f-path (AfP -> Bsh)
    {
      f32x4 c0={0,0,0,0}, c1={0,0,0,0}, c2={0,0,0,0}, c3={0,0,0,0};
      #pragma unroll 4
      for (int ks = 0; ks < 16; ++ks) {
        bf16x8 a = *(const bf16x8*)&AfP[ks*512 + lane*8];
        const ushort_t* wb = W2fp + (size_t)(ks*32 + w*4)*512 + lane*8;
        c0 = MFMA_B16(a, *(const bf16x8*)(wb       ), c0);
        c1 = MFMA_B16(a, *(const bf16x8*)(wb +  512), c1);
        c2 = MFMA_B16(a, *(const bf16x8*)(wb + 1024), c2);
        c3 = MFMA_B16(a, *(const bf16x8*)(wb + 1536), c3);
      }
      P2E(c0, 0, fb2) P2E(c1, 1, fb2) P2E(c2, 2, fb2) P2E(c3, 3, fb2)
    }
    __syncthreads();                                   // bar4

    // P3f: layer3 f-path (waves 0-3), Bsh -> fzL
    if (w < 4) {
      f32x4 acc = {0,0,0,0};
      #pragma unroll 4
      for (int ks = 0; ks < 16; ++ks) {
        bf16x8 a = *(const bf16x8*)&Bsh[ks*512 + lane*8];
        bf16x8 b = *(const bf16x8*)(W3fp + (size_t)(ks*4 + w)*512 + lane*8);
        acc = MFMA_B16(a, b, acc);
      }
      int cl = w*16 + (lane & 15);
      float bv = fb3[cl];
      #pragma unroll
      for (int j = 0; j < 4; ++j) fzL[((lane>>4)*4 + j)*64 + cl] = acc[j] + bv;
    }
    __syncthreads();                                   // bar5

    // P2h: layer2 h-path (AhP -> Bsh, reuse buffer)
    {
      f32x4 c0={0,0,0,0}, c1={0,0,0,0}, c2={0,0,0,0}, c3={0,0,0,0};
      #pragma unroll 4
      for (int ks = 0; ks < 16; ++ks) {
        bf16x8 a = *(const bf16x8*)&AhP[ks*512 + lane*8];
        const ushort_t* wb = W2hp + (size_t)(ks*32 + w*4)*512 + lane*8;
        c0 = MFMA_B16(a, *(const bf16x8*)(wb       ), c0);
        c1 = MFMA_B16(a, *(const bf16x8*)(wb +  512), c1);
        c2 = MFMA_B16(a, *(const bf16x8*)(wb + 1024), c2);
        c3 = MFMA_B16(a, *(const bf16x8*)(wb + 1536), c3);
      }
      P2E(c0, 0, hb2) P2E(c1, 1, hb2) P2E(c2, 2, hb2) P2E(c3, 3, hb2)
    }
    __syncthreads();                                   // bar6

    // P3h: layer3 h-path (waves 4-7), Bsh -> hzL
    if (w >= 4) {
      int nt = w - 4;
      f32x4 acc = {0,0,0,0};
      #pragma unroll 4
      for (int ks = 0; ks < 16; ++ks) {
        bf16x8 a = *(const bf16x8*)&Bsh[ks*512 + lane*8];
        bf16x8 b = *(const bf16x8*)(W3hp + (size_t)(ks*4 + nt)*512 + lane*8);
        acc = MFMA_B16(a, b, acc);
      }
      int cl = nt*16 + (lane & 15);
      float bv = hb3[cl];
      #pragma unroll
      for (int j = 0; j < 4; ++j) hzL[((lane>>4)*4 + j)*64 + cl] = acc[j] + bv;
    }
    __syncthreads();                                   // bar7

    // P4: epilogue — g via LUT, u, dlog, z update, repack z to Apack
    {
      float dt = ts[t+1] - ts[t];
      float sqdt = sqrtf(dt);
      float2 dwv = *(const float2*)&dW[((size_t)t*BB + b0 + erow)*LL + el0];
      float dwarr[2] = {dwv.x, dwv.y};
      float sq = 0.f;
      #pragma unroll
      for (int e = 0; e < 2; ++e) {
        int l = el0 + e;
        float zv = z_s[erow*64 + l];
        float gz;
        if (__builtin_expect(fabsf(zv) < 63.9f, 1)) {
          float x = (zv - GZMIN)*GSCALE;
          int jx = (int)x;
          float fr = x - (float)jx;
          const float* gt = &gtab[l*GK + jx];
          float g0v = gt[0], g1v = gt[1];
          gz = g0v + (g1v - g0v)*fr;
        } else {
          float s = 0.f;
          for (int h = 0; h < 512; ++h)
            s += softplus_f(zv*gw1[l*512+h] + gb1[l*512+h]) * gw2[l*512+h];
          gz = sigmoid_f(s + gb2[l]);
        }
        float fzv = fzL[erow*64 + l], hzv = hzL[erow*64 + l];
        float u = (fzv - hzv)/gz;
        sq += u*u;
        float zn = zv + fzv*dt + gz*sqdt*dwarr[e];
        z_s[erow*64 + l] = zn;
        Apack[AP_SCAT(erow, l)] = (__bf16)zn;
      }
      #pragma unroll
      for (int off = 16; off; off >>= 1) sq += __shfl_xor(sq, off);
      if ((tid & 31) == 0) dlog_s[erow] += 0.5f*sq*dt;
    }
    __syncthreads();                                   // bar8

    // P5: projection of z_{t+1}
    {
      int row = tid >> 5, d0 = tid & 31;
      float acc = projb[d0];
      #pragma unroll 8
      for (int l = 0; l < 64; ++l) acc += z_s[row*64 + l]*projW[l*DD + d0];
      out[((size_t)(b0+row)*TT + (t+1))*DD + d0] = acc;
    }
  }

  if (tid < 16) out[(size_t)BB*TT*DD + b0 + tid] = lq0_s[tid] - dlog_s[tid];
}

extern "C" void kernel_launch(void* const* d_in, const int* in_sizes, int n_in,
                              void* d_out, int out_size, void* d_ws, size_t ws_size,
                              hipStream_t stream)
{
  const float* xs   = (const float*)d_in[0];
  const float* ts   = (const float*)d_in[1];
  const float* eps0 = (const float*)d_in[2];
  const float* dW   = (const float*)d_in[3];
  const float* gruWx= (const float*)d_in[4];
  const float* gruWh= (const float*)d_in[5];
  const float* grub = (const float*)d_in[6];
  const float* encW = (const float*)d_in[7];
  const float* encb = (const float*)d_in[8];
  const float* qzW  = (const float*)d_in[9];
  const float* qzb  = (const float*)d_in[10];
  const float* fW1  = (const float*)d_in[11];
  const float* fb1  = (const float*)d_in[12];
  const float* fW2  = (const float*)d_in[13];
  const float* fb2  = (const float*)d_in[14];
  const float* fW3  = (const float*)d_in[15];
  const float* fb3  = (const float*)d_in[16];
  const float* hW1  = (const float*)d_in[17];
  const float* hb1  = (const float*)d_in[18];
  const float* hW2  = (const float*)d_in[19];
  const float* hb2  = (const float*)d_in[20];
  const float* hW3  = (const float*)d_in[21];
  const float* hb3  = (const float*)d_in[22];
  const float* gw1  = (const float*)d_in[23];
  const float* gb1  = (const float*)d_in[24];
  const float* gw2  = (const float*)d_in[25];
  const float* gb2  = (const float*)d_in[26];
  const float* projW= (const float*)d_in[27];
  const float* projb= (const float*)d_in[28];
  const float* pm   = (const float*)d_in[29];
  const float* pls  = (const float*)d_in[30];
  float* out = (float*)d_out;
  float* ws  = (float*)d_ws;

  float* ctx  = ws;                              // 16,777,216 f32
  float* gtab = ctx + (size_t)16777216;          // 262,208 f32
  ushort_t* W1fp  = (ushort_t*)(gtab + 262208);  // 98,304
  ushort_t* W1hp  = W1fp + 98304;                // 32,768
  ushort_t* W2fp  = W1hp + 32768;                // 262,144
  ushort_t* W2hp  = W2fp + 262144;               // 262,144
  ushort_t* W3fp  = W2hp + 262144;               // 32,768
  ushort_t* W3hp  = W3fp + 32768;                // 32,768
  ushort_t* Wg    = W3hp + 32768;                // 295,936
  ushort_t* encWb = Wg + 295936;                 // 32,768  (~70.3 MB total)

  hipLaunchKernelGGL(prep_kernel, dim3(3233), dim3(256), 0, stream,
                     fW1, hW1, fW2, hW2, fW3, hW3, gruWx, gruWh, encW,
                     W1fp, W1hp, W2fp, W2hp, W3fp, W3hp, Wg, encWb);
  hipLaunchKernelGGL(lut_kernel, dim3(1025), dim3(256), 0, stream,
                     gw1, gb1, gw2, gb2, gtab);
  hipLaunchKernelGGL(gru_kernel, dim3(256), dim3(512), 0, stream,
                     xs, ts, Wg, grub, encWb, encb, ctx);
  hipLaunchKernelGGL(sde_kernel, dim3(32), dim3(512), 0, stream,
                     ctx, ts, eps0, dW, qzW, qzb, pm, pls,
                     W1fp, W1hp, W2fp, W2hp, W3fp, W3hp,
                     fb1, hb1, fb2, hb2, fb3, hb3,
                     gtab, gw1, gb1, gw2, gb2, projW, projb, out);
}